// Round 1
// baseline (1376.301 us; speedup 1.0000x reference)
//
#include <hip/hip_runtime.h>

#define T_DIM 8192
#define T4    2048   // T_DIM/4
#define D_DIM 256
#define N_DIM 64

// Workspace layout (floats):
//   DH     [64][8192]   offset 0
//   lb     [8192]       offset 64*8192
//   rowsum [8192]       offset 64*8192 + 8192

// ---------------------------------------------------------------------------
// K1: DH[n][t] = sum_d D[n][d] * H[d][t]      (grid 128, block 256)
// ---------------------------------------------------------------------------
__global__ __launch_bounds__(256) void k_dh(const float* __restrict__ H,
                                            const float* __restrict__ Dm,
                                            float* __restrict__ DH) {
  __shared__ float Dl[N_DIM * 64];  // [n][64 d-chunk]
  __shared__ float Hl[64 * 64];     // [64 d-chunk][64 t]
  const int tid = threadIdx.x;
  const int t0 = blockIdx.x * 64;
  const float4* H4 = (const float4*)H;
  const float4* D4 = (const float4*)Dm;
  float4* Dl4 = (float4*)Dl;
  float4* Hl4 = (float4*)Hl;
  const int tl = tid & 63;
  const int ng = tid >> 6;  // n base = ng*16
  float acc[16];
#pragma unroll
  for (int i = 0; i < 16; ++i) acc[i] = 0.f;
  for (int dc = 0; dc < 4; ++dc) {
    __syncthreads();
#pragma unroll
    for (int r = 0; r < 4; ++r) {
      int idx = r * 256 + tid;          // 1024 float4 each
      int row = idx >> 4, c = idx & 15; // row: n (for D) / d-local (for H)
      Dl4[idx] = D4[row * 64 + dc * 16 + c];               // D row = 64 f4
      Hl4[idx] = H4[(dc * 64 + row) * T4 + (t0 >> 2) + c]; // H row = 2048 f4
    }
    __syncthreads();
    for (int dd = 0; dd < 64; dd += 4) {
      float h0 = Hl[(dd + 0) * 64 + tl];
      float h1 = Hl[(dd + 1) * 64 + tl];
      float h2 = Hl[(dd + 2) * 64 + tl];
      float h3 = Hl[(dd + 3) * 64 + tl];
#pragma unroll
      for (int i = 0; i < 16; ++i) {
        float4 dv = Dl4[(ng * 16 + i) * 16 + (dd >> 2)];
        acc[i] += dv.x * h0 + dv.y * h1 + dv.z * h2 + dv.w * h3;
      }
    }
  }
#pragma unroll
  for (int i = 0; i < 16; ++i)
    DH[(ng * 16 + i) * T_DIM + t0 + tl] = acc[i];
}

// ---------------------------------------------------------------------------
// K2: lb[t] = -0.5*sum_n DH[n][t]^2 ; rowsum[t]=0 ; Z=0   (grid 8192)
// ---------------------------------------------------------------------------
__global__ __launch_bounds__(256) void k_init(const float* __restrict__ DH,
                                              float* __restrict__ lb,
                                              float* __restrict__ rowsum,
                                              float* __restrict__ Z) {
  const int gid = blockIdx.x * 256 + threadIdx.x;  // covers 2,097,152
  Z[gid] = 0.f;
  if (gid < T_DIM) {
    float s = 0.f;
#pragma unroll 8
    for (int n = 0; n < N_DIM; ++n) {
      float v = DH[n * T_DIM + gid];
      s += v * v;
    }
    lb[gid] = -0.5f * s;
    rowsum[gid] = 0.f;
  }
}

// ---------------------------------------------------------------------------
// K3: rowsum[t] = sum_j exp(S[t][j] + lb[j])             (grid 256, block 256)
//     block: 128-t tile x 2048-j range (4 j-splits), 8x8 per-thread blocking
// ---------------------------------------------------------------------------
__global__ __launch_bounds__(256) void k_rowsum(const float* __restrict__ DH,
                                                const float* __restrict__ lb,
                                                float* __restrict__ rowsum) {
  __shared__ float At[32 * 128];   // [n-half][128 t]
  __shared__ float Bj[32 * 128];   // [n-half][128 j]
  __shared__ float lbj[128];
  __shared__ float red[16 * 128];
  const int tid = threadIdx.x;
  const int t0 = (blockIdx.x >> 2) * 128;
  const int js = blockIdx.x & 3;
  const float4* DH4 = (const float4*)DH;
  float4* At4 = (float4*)At;
  float4* Bj4 = (float4*)Bj;
  const int tq = tid & 15;  // t rows tq*8..
  const int jq = tid >> 4;  // j cols jq*8..
  float racc[8];
#pragma unroll
  for (int r = 0; r < 8; ++r) racc[r] = 0.f;
  for (int jt = 0; jt < 16; ++jt) {
    const int j0 = js * 2048 + jt * 128;
    float acc[8][8];
#pragma unroll
    for (int r = 0; r < 8; ++r)
#pragma unroll
      for (int c = 0; c < 8; ++c) acc[r][c] = 0.f;
    for (int nh = 0; nh < 2; ++nh) {
      __syncthreads();
#pragma unroll
      for (int r = 0; r < 4; ++r) {
        int idx = r * 256 + tid;  // 1024 f4 = 32 rows x 32 f4
        int np = idx >> 5, cc = idx & 31;
        At4[idx] = DH4[(nh * 32 + np) * T4 + (t0 >> 2) + cc];
        Bj4[idx] = DH4[(nh * 32 + np) * T4 + (j0 >> 2) + cc];
      }
      if (nh == 0 && tid < 128) lbj[tid] = lb[j0 + tid];
      __syncthreads();
#pragma unroll 4
      for (int np = 0; np < 32; ++np) {
        float4 a0 = At4[np * 32 + tq * 2];
        float4 a1 = At4[np * 32 + tq * 2 + 1];
        float4 b0 = Bj4[np * 32 + jq * 2];
        float4 b1 = Bj4[np * 32 + jq * 2 + 1];
        float av[8] = {a0.x, a0.y, a0.z, a0.w, a1.x, a1.y, a1.z, a1.w};
        float bv[8] = {b0.x, b0.y, b0.z, b0.w, b1.x, b1.y, b1.z, b1.w};
#pragma unroll
        for (int r = 0; r < 8; ++r)
#pragma unroll
          for (int c = 0; c < 8; ++c) acc[r][c] += av[r] * bv[c];
      }
    }
#pragma unroll
    for (int r = 0; r < 8; ++r)
#pragma unroll
      for (int c = 0; c < 8; ++c)
        racc[r] += __expf(acc[r][c] + lbj[jq * 8 + c]);
  }
  __syncthreads();
#pragma unroll
  for (int r = 0; r < 8; ++r) red[jq * 128 + tq * 8 + r] = racc[r];
  __syncthreads();
  if (tid < 128) {
    float s = 0.f;
#pragma unroll
    for (int g = 0; g < 16; ++g) s += red[g * 128 + tid];
    atomicAdd(&rowsum[t0 + tid], s);
  }
}

// ---------------------------------------------------------------------------
// K4: Z[d][j] = l2 * sum_t H[d][t] * exp(S[t][j]+lb[j]) / rowsum[t]
//     grid 256 = 128 j-tiles (64 wide) x 2 t-halves; S recomputed per t-tile.
//     LDS union is exactly 64 KB.
// ---------------------------------------------------------------------------
__global__ __launch_bounds__(256) void k_z(const float* __restrict__ H,
                                           const float* __restrict__ DH,
                                           const float* __restrict__ lb,
                                           const float* __restrict__ rowsum,
                                           const float* __restrict__ l2p,
                                           float* __restrict__ Z) {
  union SmemU {
    struct {
      float BjL[64 * 64];  // DH[:, j-tile]        [n][64 j]
      float At[64 * 32];   // DH[:, t-tile]        [n][32 t]
      float Hs[32 * 256];  // H tile transposed    [t][256 d] (xor-swizzled)
      float P[32 * 64];    // attn tile            [t][64 j]  (xor-swizzled)
    } a;
    float Zl[128 * 65];    // epilogue staging (half of d at a time)
  };
  __shared__ SmemU sm;
  const int tid = threadIdx.x;
  const int jt = blockIdx.x >> 1;
  const int th = blockIdx.x & 1;
  const int j0 = jt * 64;
  const float l2v = l2p[0];
  const float4* DH4 = (const float4*)DH;
  const float4* H4 = (const float4*)H;
  const int st = tid & 15, sj = tid >> 4;  // S-phase: t = st*2+r, j = sj*4+c
  const int dq = tid & 31, jq = tid >> 5;  // Z-phase: d = dq+32k, j = jq*8+m
  // preload DH j-tile (constant over the whole block)
  float4* BjL4 = (float4*)sm.a.BjL;
#pragma unroll
  for (int r = 0; r < 4; ++r) {
    int idx = r * 256 + tid;  // 1024 f4
    int n = idx >> 4, jc = idx & 15;
    BjL4[idx] = DH4[n * T4 + (j0 >> 2) + jc];
  }
  float lbv[4];
#pragma unroll
  for (int c = 0; c < 4; ++c) lbv[c] = lb[j0 + sj * 4 + c];
  float acc[8][8];
#pragma unroll
  for (int k = 0; k < 8; ++k)
#pragma unroll
    for (int m = 0; m < 8; ++m) acc[k][m] = 0.f;
  float4* At4 = (float4*)sm.a.At;
  for (int it = 0; it < 128; ++it) {
    const int t0 = th * 4096 + it * 32;
    __syncthreads();
    // stage DH t-tile [64 n][32 t]
#pragma unroll
    for (int r = 0; r < 2; ++r) {
      int idx = r * 256 + tid;  // 512 f4
      int n = idx >> 3, tc = idx & 7;
      At4[idx] = DH4[n * T4 + (t0 >> 2) + tc];
    }
    // stage H tile transposed -> Hs[t][d], column xor-swizzle vs bank conflicts
#pragma unroll
    for (int r = 0; r < 8; ++r) {
      int idx = r * 256 + tid;  // 2048 f4
      int d = idx >> 3, tc = idx & 7;
      float4 v = H4[d * T4 + (t0 >> 2) + tc];
      int t_;
      t_ = tc * 4 + 0; sm.a.Hs[t_ * 256 + (d ^ ((t_ & 15) << 2))] = v.x;
      t_ = tc * 4 + 1; sm.a.Hs[t_ * 256 + (d ^ ((t_ & 15) << 2))] = v.y;
      t_ = tc * 4 + 2; sm.a.Hs[t_ * 256 + (d ^ ((t_ & 15) << 2))] = v.z;
      t_ = tc * 4 + 3; sm.a.Hs[t_ * 256 + (d ^ ((t_ & 15) << 2))] = v.w;
    }
    const float rs0 = rowsum[t0 + st * 2];
    const float rs1 = rowsum[t0 + st * 2 + 1];
    __syncthreads();
    // ---- S phase: S[t][j] for this 32x64 tile (2t x 4j per thread) ----
    float sv[2][4];
#pragma unroll
    for (int r = 0; r < 2; ++r)
#pragma unroll
      for (int c = 0; c < 4; ++c) sv[r][c] = 0.f;
#pragma unroll 8
    for (int n = 0; n < N_DIM; ++n) {
      const float2 aa = *(const float2*)&sm.a.At[n * 32 + st * 2];
      const float4 bb = *(const float4*)&sm.a.BjL[n * 64 + sj * 4];
      sv[0][0] += aa.x * bb.x; sv[0][1] += aa.x * bb.y;
      sv[0][2] += aa.x * bb.z; sv[0][3] += aa.x * bb.w;
      sv[1][0] += aa.y * bb.x; sv[1][1] += aa.y * bb.y;
      sv[1][2] += aa.y * bb.z; sv[1][3] += aa.y * bb.w;
    }
    const float ri0 = 1.0f / rs0;
    const float ri1 = 1.0f / rs1;
    const int tl0 = st * 2, tl1 = st * 2 + 1;
    const int sw0 = (tl0 & 15) << 2, sw1 = (tl1 & 15) << 2;
#pragma unroll
    for (int c = 0; c < 4; ++c) {
      sm.a.P[tl0 * 64 + ((sj * 4 + c) ^ sw0)] = __expf(sv[0][c] + lbv[c]) * ri0;
      sm.a.P[tl1 * 64 + ((sj * 4 + c) ^ sw1)] = __expf(sv[1][c] + lbv[c]) * ri1;
    }
    __syncthreads();
    // ---- Z phase: acc[k][m] += H[dq+32k][t] * P[t][jq*8+m] ----
#pragma unroll 2
    for (int t = 0; t < 32; ++t) {
      const int sw = (t & 15) << 2;
      float pv[8], hv[8];
#pragma unroll
      for (int m = 0; m < 8; ++m) pv[m] = sm.a.P[t * 64 + ((jq * 8 + m) ^ sw)];
#pragma unroll
      for (int k = 0; k < 8; ++k) hv[k] = sm.a.Hs[t * 256 + ((dq + 32 * k) ^ sw)];
#pragma unroll
      for (int k = 0; k < 8; ++k)
#pragma unroll
        for (int m = 0; m < 8; ++m) acc[k][m] += hv[k] * pv[m];
    }
  }
  // epilogue: stage to LDS (two d-halves), coalesced atomicAdd into Z
#pragma unroll
  for (int half = 0; half < 2; ++half) {
    __syncthreads();
#pragma unroll
    for (int k2 = 0; k2 < 4; ++k2)
#pragma unroll
      for (int m = 0; m < 8; ++m)
        sm.Zl[(dq + 32 * k2) * 65 + jq * 8 + m] = acc[half * 4 + k2][m];
    __syncthreads();
#pragma unroll
    for (int r = 0; r < 32; ++r) {
      int idx = r * 256 + tid;  // 8192 elems
      int dd = idx >> 6, jj = idx & 63;
      atomicAdd(&Z[(half * 128 + dd) * T_DIM + j0 + jj],
                sm.Zl[dd * 65 + jj] * l2v);
    }
  }
}

// ---------------------------------------------------------------------------
extern "C" void kernel_launch(void* const* d_in, const int* in_sizes, int n_in,
                              void* d_out, int out_size, void* d_ws,
                              size_t ws_size, hipStream_t stream) {
  (void)in_sizes; (void)n_in; (void)out_size; (void)ws_size;
  const float* H = (const float*)d_in[0];    // [256][8192]
  const float* Dm = (const float*)d_in[1];   // [64][256]
  const float* l2 = (const float*)d_in[2];   // scalar
  float* Z = (float*)d_out;                  // [256][8192]
  float* DH = (float*)d_ws;                  // [64][8192]
  float* lb = DH + N_DIM * T_DIM;            // [8192]
  float* rowsum = lb + T_DIM;                // [8192]

  k_dh<<<T_DIM / 64, 256, 0, stream>>>(H, Dm, DH);
  k_init<<<(D_DIM * T_DIM) / 256, 256, 0, stream>>>(DH, lb, rowsum, Z);
  k_rowsum<<<256, 256, 0, stream>>>(DH, lb, rowsum);
  k_z<<<256, 256, 0, stream>>>(H, DH, lb, rowsum, l2, Z);
}

// Round 2
// 229.270 us; speedup vs baseline: 6.0030x; 6.0030x over previous
//
#include <hip/hip_runtime.h>

#define T_DIM 8192
#define D_DIM 256
#define N_DIM 64

typedef __bf16 bf16x8 __attribute__((ext_vector_type(8)));
typedef __bf16 bf16x4 __attribute__((ext_vector_type(4)));
typedef float f32x16 __attribute__((ext_vector_type(16)));

__device__ __forceinline__ f32x16 zero16() {
  f32x16 v;
#pragma unroll
  for (int i = 0; i < 16; ++i) v[i] = 0.f;
  return v;
}

// ---------------------------------------------------------------------------
// K1: DH = D @ H; writes DHbT[t][n] (bf16), lb[t], rowsum[t]=0. grid 128x256.
// ---------------------------------------------------------------------------
__global__ __launch_bounds__(256) void k_dh(const float* __restrict__ H,
                                            const float* __restrict__ Dm,
                                            __bf16* __restrict__ DHbT,
                                            float* __restrict__ lb,
                                            float* __restrict__ rowsum) {
  __shared__ float Dl[N_DIM * 64];
  __shared__ float Hl[64 * 64];
  __shared__ float redL[4 * 64];
  const int tid = threadIdx.x;
  const int t0 = blockIdx.x * 64;
  const float4* H4 = (const float4*)H;
  const float4* D4 = (const float4*)Dm;
  float4* Dl4 = (float4*)Dl;
  float4* Hl4 = (float4*)Hl;
  const int tl = tid & 63;
  const int ng = tid >> 6;  // n base = ng*16
  float acc[16];
#pragma unroll
  for (int i = 0; i < 16; ++i) acc[i] = 0.f;
  for (int dc = 0; dc < 4; ++dc) {
    __syncthreads();
#pragma unroll
    for (int r = 0; r < 4; ++r) {
      int idx = r * 256 + tid;
      int row = idx >> 4, c = idx & 15;
      Dl4[idx] = D4[row * 64 + dc * 16 + c];
      Hl4[idx] = H4[(dc * 64 + row) * (T_DIM / 4) + (t0 >> 2) + c];
    }
    __syncthreads();
    for (int dd = 0; dd < 64; dd += 4) {
      float h0 = Hl[(dd + 0) * 64 + tl];
      float h1 = Hl[(dd + 1) * 64 + tl];
      float h2 = Hl[(dd + 2) * 64 + tl];
      float h3 = Hl[(dd + 3) * 64 + tl];
#pragma unroll
      for (int i = 0; i < 16; ++i) {
        float4 dv = Dl4[(ng * 16 + i) * 16 + (dd >> 2)];
        acc[i] += dv.x * h0 + dv.y * h1 + dv.z * h2 + dv.w * h3;
      }
    }
  }
  // write DHbT[t][n] bf16 (16 contiguous n per thread)
  bf16x8 w0, w1;
#pragma unroll
  for (int i = 0; i < 8; ++i) { w0[i] = (__bf16)acc[i]; w1[i] = (__bf16)acc[8 + i]; }
  __bf16* dst = DHbT + (size_t)(t0 + tl) * N_DIM + ng * 16;
  *(bf16x8*)dst = w0;
  *(bf16x8*)(dst + 8) = w1;
  // lb reduce
  float partial = 0.f;
#pragma unroll
  for (int i = 0; i < 16; ++i) partial += acc[i] * acc[i];
  redL[ng * 64 + tl] = partial;
  __syncthreads();
  if (tid < 64) {
    float s = redL[tid] + redL[64 + tid] + redL[128 + tid] + redL[192 + tid];
    lb[t0 + tid] = -0.5f * s;
    rowsum[t0 + tid] = 0.f;
  }
}

// ---------------------------------------------------------------------------
// K1b: Hbf = bf16(H)   grid 1024x256
// ---------------------------------------------------------------------------
__global__ __launch_bounds__(256) void k_hbf(const float* __restrict__ H,
                                             __bf16* __restrict__ Hbf) {
  const int idx = blockIdx.x * 256 + threadIdx.x;  // 262144 threads, 8 elems each
  const float4* H4 = (const float4*)H;
  float4 v0 = H4[idx * 2], v1 = H4[idx * 2 + 1];
  bf16x8 w;
  w[0] = (__bf16)v0.x; w[1] = (__bf16)v0.y; w[2] = (__bf16)v0.z; w[3] = (__bf16)v0.w;
  w[4] = (__bf16)v1.x; w[5] = (__bf16)v1.y; w[6] = (__bf16)v1.z; w[7] = (__bf16)v1.w;
  *(bf16x8*)(Hbf + (size_t)idx * 8) = w;
}

// ---------------------------------------------------------------------------
// K2: rowsum[t] += sum_j exp(S[t][j]+lb[j])  via MFMA. grid 512x256.
//     block: t-tile 64 (bx>>2), j-range 2048 (bx&3), 32 j-iters of 64.
// ---------------------------------------------------------------------------
__global__ __launch_bounds__(256) void k_rowsum(const __bf16* __restrict__ DHbT,
                                                const float* __restrict__ lb,
                                                float* __restrict__ rowsum) {
  __shared__ float red2[64 * 65];
  const int tid = threadIdx.x;
  const int lane = tid & 63;
  const int wave = tid >> 6;       // 4 waves
  const int h = lane >> 5;
  const int tt = wave & 1, jt = wave >> 1;
  const int t0 = (blockIdx.x >> 2) * 64;
  const int jbase = (blockIdx.x & 3) * 2048;
  // preload A fragments (t rows, constant per block)
  const int t_row = t0 + tt * 32 + (lane & 31);
  bf16x8 aR[4];
#pragma unroll
  for (int kk = 0; kk < 4; ++kk)
    aR[kk] = *(const bf16x8*)(DHbT + (size_t)t_row * N_DIM + kk * 16 + h * 8);
  float racc[16];
#pragma unroll
  for (int r = 0; r < 16; ++r) racc[r] = 0.f;
  for (int jit = 0; jit < 32; ++jit) {
    const int jrow = jbase + jit * 64 + jt * 32 + (lane & 31);
    f32x16 s = zero16();
#pragma unroll
    for (int kk = 0; kk < 4; ++kk) {
      bf16x8 b = *(const bf16x8*)(DHbT + (size_t)jrow * N_DIM + kk * 16 + h * 8);
      s = __builtin_amdgcn_mfma_f32_32x32x16_bf16(aR[kk], b, s, 0, 0, 0);
    }
    const float lbv = lb[jrow];
#pragma unroll
    for (int r = 0; r < 16; ++r) racc[r] += __expf(s[r] + lbv);
  }
  // reduce over j (columns) into rowsum[t]
#pragma unroll
  for (int r = 0; r < 16; ++r) {
    int tl = tt * 32 + (r & 3) + 8 * (r >> 2) + 4 * h;
    red2[tl * 65 + jt * 32 + (lane & 31)] = racc[r];
  }
  __syncthreads();
  if (tid < 64) {
    float s = 0.f;
#pragma unroll 8
    for (int c = 0; c < 64; ++c) s += red2[tid * 65 + c];
    atomicAdd(&rowsum[t0 + tid], s);
  }
}

// ---------------------------------------------------------------------------
// K3: Z[d][j] += l2 * sum_t H[d][t] * exp(S[t][j]+lb[j]) / rowsum[t]
//     grid 256 = 64 j-tiles(128) x 4 t-splits(2048). block 512 (8 waves).
//     Per t-iter(64): S(64x128) via MFMA -> P bf16 -> LDS (swizzled) ->
//     Z += Hs(256x64) @ P(64x128), 2x2 register tiles/wave.
// ---------------------------------------------------------------------------
template <int USE_HBF>
__global__ __launch_bounds__(512) void k_z(const float* __restrict__ H,
                                           const __bf16* __restrict__ Hbf,
                                           const __bf16* __restrict__ DHbT,
                                           const float* __restrict__ lb,
                                           const float* __restrict__ rowsum,
                                           const float* __restrict__ l2p,
                                           float* __restrict__ Z) {
  __shared__ __bf16 Hs[256 * 64];   // [d][t-blocks swizzled]  32 KB
  __shared__ __bf16 Pt[128 * 64];   // [j][t-blocks swizzled]  16 KB
  __shared__ float rinvL[2048];     // 8 KB
  const int tid = threadIdx.x;
  const int lane = tid & 63;
  const int wave = tid >> 6;
  const int h = lane >> 5;
  const int jt_blk = blockIdx.x >> 2;
  const int ts = blockIdx.x & 3;
  const int j0 = jt_blk * 128;
  const int tbase = ts * 2048;
  const float l2v = l2p[0];
  // wave roles
  const int s_tt = wave >> 2, s_jt = wave & 3;       // S: (tt 0..1, jt 0..3)
  const int z_d0 = (wave & 3) * 2, z_j0 = (wave >> 2) * 2;  // Z: 2x2 of 32-tiles
  // rinv preload for this block's t-range
  for (int i = tid; i < 2048; i += 512) rinvL[i] = 1.0f / rowsum[tbase + i];
  // preload S-phase B fragments (j rows, constant per block)
  const int jrow = j0 + s_jt * 32 + (lane & 31);
  bf16x8 bS[4];
#pragma unroll
  for (int kk = 0; kk < 4; ++kk)
    bS[kk] = *(const bf16x8*)(DHbT + (size_t)jrow * N_DIM + kk * 16 + h * 8);
  const float lbv = lb[jrow];
  f32x16 acc[2][2];
#pragma unroll
  for (int a = 0; a < 2; ++a)
#pragma unroll
    for (int b = 0; b < 2; ++b) acc[a][b] = zero16();

  for (int it = 0; it < 32; ++it) {
    const int t0 = tbase + it * 64;
    __syncthreads();  // prev Z-phase reads done; rinvL ready on iter 0
    // ---- stage H tile [256 d][64 t] bf16, 8-elem-block XOR swizzle ----
#pragma unroll
    for (int r = 0; r < 4; ++r) {
      int idx = r * 512 + tid;       // 2048 chunks of 8
      int d = idx >> 3, tb = idx & 7;
      bf16x8 w;
      if (USE_HBF) {
        w = *(const bf16x8*)(Hbf + (size_t)d * T_DIM + t0 + tb * 8);
      } else {
        const float4* hp = (const float4*)(H + (size_t)d * T_DIM + t0 + tb * 8);
        float4 v0 = hp[0], v1 = hp[1];
        w[0] = (__bf16)v0.x; w[1] = (__bf16)v0.y; w[2] = (__bf16)v0.z; w[3] = (__bf16)v0.w;
        w[4] = (__bf16)v1.x; w[5] = (__bf16)v1.y; w[6] = (__bf16)v1.z; w[7] = (__bf16)v1.w;
      }
      *(bf16x8*)&Hs[d * 64 + ((tb ^ (d & 7)) << 3)] = w;
    }
    // ---- S phase: S tile (32t x 32j) per wave; A from global ----
    {
      const int t_row = t0 + s_tt * 32 + (lane & 31);
      f32x16 s = zero16();
#pragma unroll
      for (int kk = 0; kk < 4; ++kk) {
        bf16x8 a = *(const bf16x8*)(DHbT + (size_t)t_row * N_DIM + kk * 16 + h * 8);
        s = __builtin_amdgcn_mfma_f32_32x32x16_bf16(a, bS[kk], s, 0, 0, 0);
      }
      // P = exp(S+lb)*rinv -> bf16 -> Pt[j][t] swizzled
      const int jl = s_jt * 32 + (lane & 31);
#pragma unroll
      for (int q = 0; q < 4; ++q) {
        const int tl = s_tt * 32 + 8 * q + 4 * h;  // 4 contiguous t from here
        const float4 rv = *(const float4*)&rinvL[it * 64 + tl];
        bf16x4 pv;
        pv[0] = (__bf16)(__expf(s[q * 4 + 0] + lbv) * rv.x);
        pv[1] = (__bf16)(__expf(s[q * 4 + 1] + lbv) * rv.y);
        pv[2] = (__bf16)(__expf(s[q * 4 + 2] + lbv) * rv.z);
        pv[3] = (__bf16)(__expf(s[q * 4 + 3] + lbv) * rv.w);
        const int c = tl >> 3, off = tl & 7;
        *(bf16x4*)&Pt[jl * 64 + ((c ^ (jl & 7)) << 3) + off] = pv;
      }
    }
    __syncthreads();  // Hs + Pt ready
    // ---- Z phase: acc(2x2 of 32x32) += Hs @ Pt ----
#pragma unroll
    for (int kk = 0; kk < 4; ++kk) {
      const int c = kk * 2 + h;
      const int d0 = z_d0 * 32 + (lane & 31);
      const int d1 = d0 + 32;
      const int jj0 = z_j0 * 32 + (lane & 31);
      const int jj1 = jj0 + 32;
      bf16x8 a0 = *(const bf16x8*)&Hs[d0 * 64 + ((c ^ (d0 & 7)) << 3)];
      bf16x8 a1 = *(const bf16x8*)&Hs[d1 * 64 + ((c ^ (d1 & 7)) << 3)];
      bf16x8 b0 = *(const bf16x8*)&Pt[jj0 * 64 + ((c ^ (jj0 & 7)) << 3)];
      bf16x8 b1 = *(const bf16x8*)&Pt[jj1 * 64 + ((c ^ (jj1 & 7)) << 3)];
      acc[0][0] = __builtin_amdgcn_mfma_f32_32x32x16_bf16(a0, b0, acc[0][0], 0, 0, 0);
      acc[0][1] = __builtin_amdgcn_mfma_f32_32x32x16_bf16(a0, b1, acc[0][1], 0, 0, 0);
      acc[1][0] = __builtin_amdgcn_mfma_f32_32x32x16_bf16(a1, b0, acc[1][0], 0, 0, 0);
      acc[1][1] = __builtin_amdgcn_mfma_f32_32x32x16_bf16(a1, b1, acc[1][1], 0, 0, 0);
    }
  }
  // ---- epilogue: atomic accumulate into Z ----
#pragma unroll
  for (int dt = 0; dt < 2; ++dt)
#pragma unroll
    for (int jj = 0; jj < 2; ++jj)
#pragma unroll
      for (int r = 0; r < 16; ++r) {
        int d = (z_d0 + dt) * 32 + (r & 3) + 8 * (r >> 2) + 4 * h;
        int j = j0 + (z_j0 + jj) * 32 + (lane & 31);
        atomicAdd(&Z[(size_t)d * T_DIM + j], acc[dt][jj][r] * l2v);
      }
}

// ---------------------------------------------------------------------------
extern "C" void kernel_launch(void* const* d_in, const int* in_sizes, int n_in,
                              void* d_out, int out_size, void* d_ws,
                              size_t ws_size, hipStream_t stream) {
  (void)in_sizes; (void)n_in; (void)out_size;
  const float* H = (const float*)d_in[0];
  const float* Dm = (const float*)d_in[1];
  const float* l2 = (const float*)d_in[2];
  float* Z = (float*)d_out;
  char* ws = (char*)d_ws;
  __bf16* DHbT = (__bf16*)ws;                              // 1,048,576 B
  float* lb = (float*)(ws + 1048576);                      // 32,768 B
  float* rowsum = (float*)(ws + 1048576 + 32768);          // 32,768 B
  __bf16* Hbf = (__bf16*)(ws + 1048576 + 65536);           // 4,194,304 B
  const bool use_hbf = ws_size >= (size_t)(1048576 + 65536 + 4194304);

  k_dh<<<128, 256, 0, stream>>>(H, Dm, DHbT, lb, rowsum);
  if (use_hbf) k_hbf<<<1024, 256, 0, stream>>>(H, Hbf);
  k_rowsum<<<512, 256, 0, stream>>>(DHbT, lb, rowsum);
  hipMemsetAsync(Z, 0, (size_t)D_DIM * T_DIM * sizeof(float), stream);
  if (use_hbf)
    k_z<1><<<256, 512, 0, stream>>>(H, Hbf, DHbT, lb, rowsum, l2, Z);
  else
    k_z<0><<<256, 512, 0, stream>>>(H, Hbf, DHbT, lb, rowsum, l2, Z);
}

// Round 4
// 225.969 us; speedup vs baseline: 6.0907x; 1.0146x over previous
//
#include <hip/hip_runtime.h>

#define T_DIM 8192
#define D_DIM 256
#define N_DIM 64

typedef __bf16 bf16x8 __attribute__((ext_vector_type(8)));
typedef __bf16 bf16x4 __attribute__((ext_vector_type(4)));
typedef float f32x16 __attribute__((ext_vector_type(16)));

__device__ __forceinline__ f32x16 zero16() {
  f32x16 v;
#pragma unroll
  for (int i = 0; i < 16; ++i) v[i] = 0.f;
  return v;
}

// ---------------------------------------------------------------------------
// K1: DHbT[t][n] (bf16) via split-bf16 MFMA, Hbf, lb[t], rowsum[t]=0.
//     grid 128 x 256. Per block: t-tile 64, full n=64, K=256.
// ---------------------------------------------------------------------------
__global__ __launch_bounds__(256) void k_dh(const float* __restrict__ H,
                                            const float* __restrict__ Dm,
                                            __bf16* __restrict__ Hbf,
                                            __bf16* __restrict__ DHbT,
                                            float* __restrict__ lb,
                                            float* __restrict__ rowsum) {
  __shared__ __bf16 HlThi[64 * 264];  // [t][d] hi
  __shared__ __bf16 HlTlo[64 * 264];  // [t][d] lo
  __shared__ __bf16 DHs[64 * 72];     // [t][n]
  const int tid = threadIdx.x;
  const int t0 = blockIdx.x * 64;
  const int lane = tid & 63;
  const int wave = tid >> 6;
  const int h = lane >> 5;
  const int l31 = lane & 31;
  const float4* H4 = (const float4*)H;
  // phase 1: stage FULL 256d x 64t tile transposed (hi/lo) + emit Hbf
  // r<16: 4096 float4 = 16384 floats = 256*64.  (R3 bug: r<8 covered half.)
#pragma unroll
  for (int r = 0; r < 16; ++r) {
    int idx = r * 256 + tid;
    int d = idx >> 4, tc = idx & 15;  // tc: 16 float4 = 64 t per d
    float4 v = H4[(size_t)d * (T_DIM / 4) + (t0 >> 2) + tc];
    float vv[4] = {v.x, v.y, v.z, v.w};
    bf16x4 whi;
#pragma unroll
    for (int i = 0; i < 4; ++i) {
      __bf16 hi = (__bf16)vv[i];
      float lo = vv[i] - (float)hi;
      whi[i] = hi;
      HlThi[(tc * 4 + i) * 264 + d] = hi;
      HlTlo[(tc * 4 + i) * 264 + d] = (__bf16)lo;
    }
    *(bf16x4*)(Hbf + (size_t)d * T_DIM + t0 + tc * 4) = whi;
  }
  __syncthreads();
  // phase 2: C[32t x 32n] per wave, K=256, 3-product split-bf16
  const int tt = wave & 1, nh = wave >> 1;
  const int m = tt * 32 + l31;
  const int n = nh * 32 + l31;
  f32x16 c = zero16();
  for (int kk = 0; kk < 16; ++kk) {
    bf16x8 ahi = *(const bf16x8*)&HlThi[m * 264 + kk * 16 + h * 8];
    bf16x8 alo = *(const bf16x8*)&HlTlo[m * 264 + kk * 16 + h * 8];
    const float4* dp = (const float4*)(Dm + (size_t)n * 256 + kk * 16 + h * 8);
    float4 b0 = dp[0], b1 = dp[1];
    float bv[8] = {b0.x, b0.y, b0.z, b0.w, b1.x, b1.y, b1.z, b1.w};
    bf16x8 bhi, blo;
#pragma unroll
    for (int i = 0; i < 8; ++i) {
      __bf16 hi = (__bf16)bv[i];
      bhi[i] = hi;
      blo[i] = (__bf16)(bv[i] - (float)hi);
    }
    c = __builtin_amdgcn_mfma_f32_32x32x16_bf16(ahi, bhi, c, 0, 0, 0);
    c = __builtin_amdgcn_mfma_f32_32x32x16_bf16(ahi, blo, c, 0, 0, 0);
    c = __builtin_amdgcn_mfma_f32_32x32x16_bf16(alo, bhi, c, 0, 0, 0);
  }
  // phase 3: C -> LDS [t][n] bf16
#pragma unroll
  for (int r = 0; r < 16; ++r) {
    int row = tt * 32 + (r & 3) + 8 * (r >> 2) + 4 * h;
    DHs[row * 72 + n] = (__bf16)c[r];
  }
  __syncthreads();
  {
    // full 16 elements per thread (R3 bug: only 8 of each 16 written)
    int t = tid >> 2, nq = tid & 3;
    bf16x8 w0 = *(const bf16x8*)&DHs[t * 72 + nq * 16];
    bf16x8 w1 = *(const bf16x8*)&DHs[t * 72 + nq * 16 + 8];
    __bf16* dst = DHbT + (size_t)(t0 + t) * 64 + nq * 16;
    *(bf16x8*)dst = w0;
    *(bf16x8*)(dst + 8) = w1;
  }
  if (tid < 64) {
    float s = 0.f;
#pragma unroll
    for (int q = 0; q < 8; ++q) {
      bf16x8 w = *(const bf16x8*)&DHs[tid * 72 + q * 8];
#pragma unroll
      for (int i = 0; i < 8; ++i) { float f = (float)w[i]; s += f * f; }
    }
    lb[t0 + tid] = -0.5f * s;
    rowsum[t0 + tid] = 0.f;
  }
}

// ---------------------------------------------------------------------------
// K2: rowsum[t] += sum_j exp(S[t][j]+lb[j])  via MFMA. grid 512x256.
// ---------------------------------------------------------------------------
__global__ __launch_bounds__(256) void k_rowsum(const __bf16* __restrict__ DHbT,
                                                const float* __restrict__ lb,
                                                float* __restrict__ rowsum) {
  __shared__ float red2[64 * 65];
  const int tid = threadIdx.x;
  const int lane = tid & 63;
  const int wave = tid >> 6;
  const int h = lane >> 5;
  const int tt = wave & 1, jt = wave >> 1;
  const int t0 = (blockIdx.x >> 2) * 64;
  const int jbase = (blockIdx.x & 3) * 2048;
  const int t_row = t0 + tt * 32 + (lane & 31);
  bf16x8 aR[4];
#pragma unroll
  for (int kk = 0; kk < 4; ++kk)
    aR[kk] = *(const bf16x8*)(DHbT + (size_t)t_row * N_DIM + kk * 16 + h * 8);
  float racc[16];
#pragma unroll
  for (int r = 0; r < 16; ++r) racc[r] = 0.f;
  for (int jit = 0; jit < 32; ++jit) {
    const int jrow = jbase + jit * 64 + jt * 32 + (lane & 31);
    f32x16 s = zero16();
#pragma unroll
    for (int kk = 0; kk < 4; ++kk) {
      bf16x8 b = *(const bf16x8*)(DHbT + (size_t)jrow * N_DIM + kk * 16 + h * 8);
      s = __builtin_amdgcn_mfma_f32_32x32x16_bf16(aR[kk], b, s, 0, 0, 0);
    }
    const float lbv = lb[jrow];
#pragma unroll
    for (int r = 0; r < 16; ++r) racc[r] += __expf(s[r] + lbv);
  }
#pragma unroll
  for (int r = 0; r < 16; ++r) {
    int tl = tt * 32 + (r & 3) + 8 * (r >> 2) + 4 * h;
    red2[tl * 65 + jt * 32 + (lane & 31)] = racc[r];
  }
  __syncthreads();
  if (tid < 64) {
    float s = 0.f;
#pragma unroll 8
    for (int c = 0; c < 64; ++c) s += red2[tid * 65 + c];
    atomicAdd(&rowsum[t0 + tid], s);
  }
}

// ---------------------------------------------------------------------------
// K3: Z[d][j] += l2 * sum_t H[d][t] * P[t][j]. grid 512 x 256 (4 waves).
//     Block: 256d x 128j, t-range 1024 (t-split 8), 16 iters of Kt=64.
// ---------------------------------------------------------------------------
__global__ __launch_bounds__(256, 2) void k_z(const __bf16* __restrict__ Hbf,
                                              const __bf16* __restrict__ DHbT,
                                              const float* __restrict__ lb,
                                              const float* __restrict__ rowsum,
                                              const float* __restrict__ l2p,
                                              float* __restrict__ Z) {
  __shared__ __bf16 Hs[256 * 64];  // [d][t] swizzled, 32 KB
  __shared__ __bf16 Pt[128 * 64];  // [j][t] swizzled, 16 KB
  __shared__ float rinvL[1024];    // 4 KB
  const int tid = threadIdx.x;
  const int lane = tid & 63;
  const int wave = tid >> 6;
  const int h = lane >> 5;
  const int l31 = lane & 31;
  const int j0 = (int)(blockIdx.x >> 3) * 128;
  const int tbase = (int)(blockIdx.x & 7) * 1024;
  const float l2v = l2p[0];
  const int s_tt = wave & 1, s_jg = wave >> 1;
  bf16x8 bS[2][4];
  float lbv[2];
#pragma unroll
  for (int q = 0; q < 2; ++q) {
    int jrow = j0 + (s_jg * 2 + q) * 32 + l31;
#pragma unroll
    for (int kk = 0; kk < 4; ++kk)
      bS[q][kk] = *(const bf16x8*)(DHbT + (size_t)jrow * 64 + kk * 16 + h * 8);
    lbv[q] = lb[jrow];
  }
  for (int i = tid; i < 1024; i += 256) rinvL[i] = 1.0f / rowsum[tbase + i];
  f32x16 acc[4][2];
#pragma unroll
  for (int u = 0; u < 4; ++u)
#pragma unroll
    for (int v = 0; v < 2; ++v) acc[u][v] = zero16();
  bf16x8 aR[4];
  {
    int t_row = tbase + s_tt * 32 + l31;
#pragma unroll
    for (int kk = 0; kk < 4; ++kk)
      aR[kk] = *(const bf16x8*)(DHbT + (size_t)t_row * 64 + kk * 16 + h * 8);
  }
  __syncthreads();  // rinvL ready
  for (int it = 0; it < 16; ++it) {
    const int t0 = tbase + it * 64;
#pragma unroll
    for (int r = 0; r < 8; ++r) {
      int idx = r * 256 + tid;
      int d = idx >> 3, tb = idx & 7;
      bf16x8 w = *(const bf16x8*)(Hbf + (size_t)d * T_DIM + t0 + tb * 8);
      *(bf16x8*)&Hs[d * 64 + ((tb ^ ((d ^ (d >> 3)) & 7)) << 3)] = w;
    }
#pragma unroll
    for (int q = 0; q < 2; ++q) {
      f32x16 s = zero16();
#pragma unroll
      for (int kk = 0; kk < 4; ++kk)
        s = __builtin_amdgcn_mfma_f32_32x32x16_bf16(aR[kk], bS[q][kk], s, 0, 0, 0);
      const int jl = (s_jg * 2 + q) * 32 + l31;
      const int sj = (jl ^ (jl >> 3)) & 7;
#pragma unroll
      for (int g = 0; g < 4; ++g) {
        const int tl = s_tt * 32 + g * 8 + 4 * h;
        const float4 rv = *(const float4*)&rinvL[it * 64 + tl];
        bf16x4 pv;
        pv[0] = (__bf16)(__expf(s[g * 4 + 0] + lbv[q]) * rv.x);
        pv[1] = (__bf16)(__expf(s[g * 4 + 1] + lbv[q]) * rv.y);
        pv[2] = (__bf16)(__expf(s[g * 4 + 2] + lbv[q]) * rv.z);
        pv[3] = (__bf16)(__expf(s[g * 4 + 3] + lbv[q]) * rv.w);
        const int cchunk = tl >> 3;
        *(bf16x4*)&Pt[jl * 64 + ((cchunk ^ sj) << 3) + 4 * h] = pv;
      }
    }
    __syncthreads();
#pragma unroll
    for (int kk = 0; kk < 4; ++kk) {
      const int c = kk * 2 + h;
      bf16x8 af[4], bw[2];
#pragma unroll
      for (int u = 0; u < 4; ++u) {
        int d = (wave & 1) * 128 + u * 32 + l31;
        af[u] = *(const bf16x8*)&Hs[d * 64 + ((c ^ ((d ^ (d >> 3)) & 7)) << 3)];
      }
#pragma unroll
      for (int v = 0; v < 2; ++v) {
        int j = (wave >> 1) * 64 + v * 32 + l31;
        bw[v] = *(const bf16x8*)&Pt[j * 64 + ((c ^ ((j ^ (j >> 3)) & 7)) << 3)];
      }
#pragma unroll
      for (int u = 0; u < 4; ++u)
#pragma unroll
        for (int v = 0; v < 2; ++v)
          acc[u][v] = __builtin_amdgcn_mfma_f32_32x32x16_bf16(af[u], bw[v], acc[u][v], 0, 0, 0);
    }
    if (it < 15) {
      int t_row = tbase + (it + 1) * 64 + s_tt * 32 + l31;
#pragma unroll
      for (int kk = 0; kk < 4; ++kk)
        aR[kk] = *(const bf16x8*)(DHbT + (size_t)t_row * 64 + kk * 16 + h * 8);
    }
    __syncthreads();
  }
#pragma unroll
  for (int u = 0; u < 4; ++u)
#pragma unroll
    for (int v = 0; v < 2; ++v)
#pragma unroll
      for (int r = 0; r < 16; ++r) {
        int d = (wave & 1) * 128 + u * 32 + (r & 3) + 8 * (r >> 2) + 4 * h;
        int j = j0 + (wave >> 1) * 64 + v * 32 + l31;
        atomicAdd(&Z[(size_t)d * T_DIM + j], acc[u][v][r] * l2v);
      }
}

// ---------------------------------------------------------------------------
extern "C" void kernel_launch(void* const* d_in, const int* in_sizes, int n_in,
                              void* d_out, int out_size, void* d_ws,
                              size_t ws_size, hipStream_t stream) {
  (void)in_sizes; (void)n_in; (void)out_size; (void)ws_size;
  const float* H = (const float*)d_in[0];
  const float* Dm = (const float*)d_in[1];
  const float* l2 = (const float*)d_in[2];
  float* Z = (float*)d_out;
  char* ws = (char*)d_ws;
  __bf16* DHbT = (__bf16*)ws;                      // 1,048,576 B
  float* lb = (float*)(ws + 1048576);              // 32,768 B
  float* rowsum = (float*)(ws + 1048576 + 32768);  // 32,768 B
  __bf16* Hbf = (__bf16*)(ws + 1048576 + 65536);   // 4,194,304 B

  k_dh<<<128, 256, 0, stream>>>(H, Dm, Hbf, DHbT, lb, rowsum);
  k_rowsum<<<512, 256, 0, stream>>>(DHbT, lb, rowsum);
  hipMemsetAsync(Z, 0, (size_t)D_DIM * T_DIM * sizeof(float), stream);
  k_z<<<512, 256, 0, stream>>>(Hbf, DHbT, lb, rowsum, l2, Z);
}

// Round 5
// 184.729 us; speedup vs baseline: 7.4504x; 1.2232x over previous
//
#include <hip/hip_runtime.h>

#define T_DIM 8192
#define D_DIM 256
#define N_DIM 64

typedef __bf16 bf16x8 __attribute__((ext_vector_type(8)));
typedef __bf16 bf16x4 __attribute__((ext_vector_type(4)));
typedef float f32x16 __attribute__((ext_vector_type(16)));

__device__ __forceinline__ f32x16 zero16() {
  f32x16 v;
#pragma unroll
  for (int i = 0; i < 16; ++i) v[i] = 0.f;
  return v;
}

// ---------------------------------------------------------------------------
// K1: DHbT[t][n] (bf16) via split-bf16 MFMA, lb[t], rowsum[t]=0.
//     grid 128 x 256. Per block: t-tile 64, full n=64, K=256.
// ---------------------------------------------------------------------------
__global__ __launch_bounds__(256) void k_dh(const float* __restrict__ H,
                                            const float* __restrict__ Dm,
                                            __bf16* __restrict__ DHbT,
                                            float* __restrict__ lb,
                                            float* __restrict__ rowsum) {
  __shared__ __bf16 HlThi[64 * 264];  // [t][d] hi
  __shared__ __bf16 HlTlo[64 * 264];  // [t][d] lo
  __shared__ __bf16 DHs[64 * 72];     // [t][n]
  const int tid = threadIdx.x;
  const int t0 = blockIdx.x * 64;
  const int lane = tid & 63;
  const int wave = tid >> 6;
  const int h = lane >> 5;
  const int l31 = lane & 31;
  const float4* H4 = (const float4*)H;
#pragma unroll
  for (int r = 0; r < 16; ++r) {
    int idx = r * 256 + tid;
    int d = idx >> 4, tc = idx & 15;
    float4 v = H4[(size_t)d * (T_DIM / 4) + (t0 >> 2) + tc];
    float vv[4] = {v.x, v.y, v.z, v.w};
#pragma unroll
    for (int i = 0; i < 4; ++i) {
      __bf16 hi = (__bf16)vv[i];
      float lo = vv[i] - (float)hi;
      HlThi[(tc * 4 + i) * 264 + d] = hi;
      HlTlo[(tc * 4 + i) * 264 + d] = (__bf16)lo;
    }
  }
  __syncthreads();
  const int tt = wave & 1, nh = wave >> 1;
  const int m = tt * 32 + l31;
  const int n = nh * 32 + l31;
  f32x16 c = zero16();
  for (int kk = 0; kk < 16; ++kk) {
    bf16x8 ahi = *(const bf16x8*)&HlThi[m * 264 + kk * 16 + h * 8];
    bf16x8 alo = *(const bf16x8*)&HlTlo[m * 264 + kk * 16 + h * 8];
    const float4* dp = (const float4*)(Dm + (size_t)n * 256 + kk * 16 + h * 8);
    float4 b0 = dp[0], b1 = dp[1];
    float bv[8] = {b0.x, b0.y, b0.z, b0.w, b1.x, b1.y, b1.z, b1.w};
    bf16x8 bhi, blo;
#pragma unroll
    for (int i = 0; i < 8; ++i) {
      __bf16 hi = (__bf16)bv[i];
      bhi[i] = hi;
      blo[i] = (__bf16)(bv[i] - (float)hi);
    }
    c = __builtin_amdgcn_mfma_f32_32x32x16_bf16(ahi, bhi, c, 0, 0, 0);
    c = __builtin_amdgcn_mfma_f32_32x32x16_bf16(ahi, blo, c, 0, 0, 0);
    c = __builtin_amdgcn_mfma_f32_32x32x16_bf16(alo, bhi, c, 0, 0, 0);
  }
#pragma unroll
  for (int r = 0; r < 16; ++r) {
    int row = tt * 32 + (r & 3) + 8 * (r >> 2) + 4 * h;
    DHs[row * 72 + n] = (__bf16)c[r];
  }
  __syncthreads();
  {
    int t = tid >> 2, nq = tid & 3;
    bf16x8 w0 = *(const bf16x8*)&DHs[t * 72 + nq * 16];
    bf16x8 w1 = *(const bf16x8*)&DHs[t * 72 + nq * 16 + 8];
    __bf16* dst = DHbT + (size_t)(t0 + t) * 64 + nq * 16;
    *(bf16x8*)dst = w0;
    *(bf16x8*)(dst + 8) = w1;
  }
  if (tid < 64) {
    float s = 0.f;
#pragma unroll
    for (int q = 0; q < 8; ++q) {
      bf16x8 w = *(const bf16x8*)&DHs[tid * 72 + q * 8];
#pragma unroll
      for (int i = 0; i < 8; ++i) { float f = (float)w[i]; s += f * f; }
    }
    lb[t0 + tid] = -0.5f * s;
    rowsum[t0 + tid] = 0.f;
  }
}

// ---------------------------------------------------------------------------
// K2: rowsum[t] += sum_j exp(S[t][j]+lb[j]). grid 1024 x 256 (4 blocks/CU).
//     block: t-tile 64 (bx>>3), j-range 1024 (bx&7), 16 j-iters of 64.
//     B fragments software-prefetched one jit ahead.
// ---------------------------------------------------------------------------
__global__ __launch_bounds__(256) void k_rowsum(const __bf16* __restrict__ DHbT,
                                                const float* __restrict__ lb,
                                                float* __restrict__ rowsum) {
  __shared__ float red2[64 * 65];
  const int tid = threadIdx.x;
  const int lane = tid & 63;
  const int wave = tid >> 6;
  const int h = lane >> 5;
  const int tt = wave & 1, jt = wave >> 1;
  const int t0 = (int)(blockIdx.x >> 3) * 64;
  const int jbase = (int)(blockIdx.x & 7) * 1024;
  const int t_row = t0 + tt * 32 + (lane & 31);
  bf16x8 aR[4];
#pragma unroll
  for (int kk = 0; kk < 4; ++kk)
    aR[kk] = *(const bf16x8*)(DHbT + (size_t)t_row * N_DIM + kk * 16 + h * 8);
  float racc[16];
#pragma unroll
  for (int r = 0; r < 16; ++r) racc[r] = 0.f;
  // prefetch jit=0 B fragments
  bf16x8 bN[4];
  {
    int jrow = jbase + jt * 32 + (lane & 31);
#pragma unroll
    for (int kk = 0; kk < 4; ++kk)
      bN[kk] = *(const bf16x8*)(DHbT + (size_t)jrow * N_DIM + kk * 16 + h * 8);
  }
  for (int jit = 0; jit < 16; ++jit) {
    bf16x8 bC[4];
#pragma unroll
    for (int kk = 0; kk < 4; ++kk) bC[kk] = bN[kk];
    const float lbv = lb[jbase + jit * 64 + jt * 32 + (lane & 31)];
    if (jit < 15) {
      int jrow = jbase + (jit + 1) * 64 + jt * 32 + (lane & 31);
#pragma unroll
      for (int kk = 0; kk < 4; ++kk)
        bN[kk] = *(const bf16x8*)(DHbT + (size_t)jrow * N_DIM + kk * 16 + h * 8);
    }
    f32x16 s = zero16();
#pragma unroll
    for (int kk = 0; kk < 4; ++kk)
      s = __builtin_amdgcn_mfma_f32_32x32x16_bf16(aR[kk], bC[kk], s, 0, 0, 0);
#pragma unroll
    for (int r = 0; r < 16; ++r) racc[r] += __expf(s[r] + lbv);
  }
#pragma unroll
  for (int r = 0; r < 16; ++r) {
    int tl = tt * 32 + (r & 3) + 8 * (r >> 2) + 4 * h;
    red2[tl * 65 + jt * 32 + (lane & 31)] = racc[r];
  }
  __syncthreads();
  if (tid < 64) {
    float s = 0.f;
#pragma unroll 8
    for (int c = 0; c < 64; ++c) s += red2[tid * 65 + c];
    atomicAdd(&rowsum[t0 + tid], s);
  }
}

// ---------------------------------------------------------------------------
// K2b: Hbf_sw[tblk][d][tb'] = bf16(H[d][t]*rinv[t]) pre-swizzled to k_z's LDS
//      image (tb' = tb ^ ((d^(d>>3))&7)); also zeroes Z. grid 256 x 256.
// ---------------------------------------------------------------------------
__global__ __launch_bounds__(256) void k_scaleH(const float* __restrict__ H,
                                                const float* __restrict__ rowsum,
                                                __bf16* __restrict__ Hbf_sw,
                                                float* __restrict__ Z) {
  __shared__ float rinvL[64];
  const int tid = threadIdx.x;
  const int bx = blockIdx.x;
  const int tblk = bx >> 1, dh = bx & 1;
  const int t0 = tblk * 64;
  if (tid < 64) rinvL[tid] = 1.0f / rowsum[t0 + tid];
  __syncthreads();
#pragma unroll
  for (int itr = 0; itr < 4; ++itr) {
    int idx = itr * 256 + tid;  // 1024 granules of 8
    int dl = idx >> 3, tbp = idx & 7;
    int d = dh * 128 + dl;
    int swz = (d ^ (d >> 3)) & 7;
    int tloc = (tbp ^ swz) << 3;
    const float4* hp = (const float4*)(H + (size_t)d * T_DIM + t0 + tloc);
    float4 v0 = hp[0], v1 = hp[1];
    float4 r0 = *(const float4*)&rinvL[tloc];
    float4 r1 = *(const float4*)&rinvL[tloc + 4];
    bf16x8 w;
    w[0] = (__bf16)(v0.x * r0.x); w[1] = (__bf16)(v0.y * r0.y);
    w[2] = (__bf16)(v0.z * r0.z); w[3] = (__bf16)(v0.w * r0.w);
    w[4] = (__bf16)(v1.x * r1.x); w[5] = (__bf16)(v1.y * r1.y);
    w[6] = (__bf16)(v1.z * r1.z); w[7] = (__bf16)(v1.w * r1.w);
    *(bf16x8*)(Hbf_sw + (size_t)tblk * 16384 + (size_t)d * 64 + tbp * 8) = w;
  }
  // Z zero: 2,097,152 floats = 524288 float4 over 65536 threads
  float4* Z4 = (float4*)Z;
  const int base = bx * 256 + tid;
  const float4 z4 = {0.f, 0.f, 0.f, 0.f};
#pragma unroll
  for (int r = 0; r < 8; ++r) Z4[r * 65536 + base] = z4;
}

// ---------------------------------------------------------------------------
// K3: Z[d][j] += l2 * sum_t H'[d][t] * E[t][j],  E = exp(S+lb) (rinv folded
//     into H'). grid 512 = 64 j-tiles(128) x 2 d-halves(128) x 4 t-splits.
//     block 256 thr / 4 waves, 32 iters of Kt=64. LDS 32 KB -> 3 blocks/CU.
//     Hs staged async via global_load_lds from pre-swizzled Hbf_sw.
// ---------------------------------------------------------------------------
__global__ __launch_bounds__(256, 3) void k_z(const __bf16* __restrict__ Hbf_sw,
                                              const __bf16* __restrict__ DHbT,
                                              const float* __restrict__ lb,
                                              const float* __restrict__ l2p,
                                              float* __restrict__ Z) {
  __shared__ __bf16 Hs[128 * 64];  // [dl][t] swizzled, 16 KB
  __shared__ __bf16 Pt[128 * 64];  // [j][t] swizzled, 16 KB
  const int tid = threadIdx.x;
  const int lane = tid & 63;
  const int wave = tid >> 6;
  const int h = lane >> 5;
  const int l31 = lane & 31;
  const int bx = blockIdx.x;
  const int ts = bx & 3;
  const int dh = (bx >> 2) & 1;
  const int j0 = (bx >> 3) * 128;
  const int tbase = ts * 2048;
  const float l2v = l2p[0];
  const int s_tt = wave & 1, s_jg = wave >> 1;
  // resident S-phase B fragments + lb
  bf16x8 bS[2][4];
  float lbv[2];
#pragma unroll
  for (int q = 0; q < 2; ++q) {
    int jrow = j0 + (s_jg * 2 + q) * 32 + l31;
#pragma unroll
    for (int kk = 0; kk < 4; ++kk)
      bS[q][kk] = *(const bf16x8*)(DHbT + (size_t)jrow * 64 + kk * 16 + h * 8);
    lbv[q] = lb[jrow];
  }
  f32x16 acc[2][2];
#pragma unroll
  for (int u = 0; u < 2; ++u)
#pragma unroll
    for (int v = 0; v < 2; ++v) acc[u][v] = zero16();
  // prefetch A fragments for it=0
  bf16x8 aR[4];
  {
    int t_row = tbase + s_tt * 32 + l31;
#pragma unroll
    for (int kk = 0; kk < 4; ++kk)
      aR[kk] = *(const bf16x8*)(DHbT + (size_t)t_row * 64 + kk * 16 + h * 8);
  }
  for (int it = 0; it < 32; ++it) {
    // ---- async stage Hs [128 dl][64 t] from pre-swizzled global image ----
    const __bf16* gsrc = Hbf_sw + (size_t)(ts * 32 + it) * 16384 + (size_t)dh * 8192;
#pragma unroll
    for (int r = 0; r < 4; ++r) {
      int chunk = wave * 4 + r;  // 16 chunks x 1 KB
      __builtin_amdgcn_global_load_lds(
          (const __attribute__((address_space(1))) unsigned int*)(gsrc + chunk * 512 + lane * 8),
          (__attribute__((address_space(3))) unsigned int*)(Hs + chunk * 512),
          16, 0, 0);
    }
    // ---- S phase: 2 tiles (32t x 32j) per wave; E = exp(S+lb) -> Pt ----
#pragma unroll
    for (int q = 0; q < 2; ++q) {
      f32x16 s = zero16();
#pragma unroll
      for (int kk = 0; kk < 4; ++kk)
        s = __builtin_amdgcn_mfma_f32_32x32x16_bf16(aR[kk], bS[q][kk], s, 0, 0, 0);
      const int jl = (s_jg * 2 + q) * 32 + l31;
      const int sj = (jl ^ (jl >> 3)) & 7;
#pragma unroll
      for (int g = 0; g < 4; ++g) {
        const int tl = s_tt * 32 + g * 8 + 4 * h;
        bf16x4 pv;
        pv[0] = (__bf16)__expf(s[g * 4 + 0] + lbv[q]);
        pv[1] = (__bf16)__expf(s[g * 4 + 1] + lbv[q]);
        pv[2] = (__bf16)__expf(s[g * 4 + 2] + lbv[q]);
        pv[3] = (__bf16)__expf(s[g * 4 + 3] + lbv[q]);
        const int cchunk = tl >> 3;
        *(bf16x4*)&Pt[jl * 64 + ((cchunk ^ sj) << 3) + 4 * h] = pv;
      }
    }
    __syncthreads();  // Pt written by all waves; async Hs DMA drained
    // ---- Z phase: 2x2 tiles of 32^2 per wave ----
#pragma unroll
    for (int kk = 0; kk < 4; ++kk) {
      const int c = kk * 2 + h;
      bf16x8 af[2], bw[2];
#pragma unroll
      for (int u = 0; u < 2; ++u) {
        int dl = (wave & 1) * 64 + u * 32 + l31;
        af[u] = *(const bf16x8*)&Hs[dl * 64 + ((c ^ ((dl ^ (dl >> 3)) & 7)) << 3)];
      }
#pragma unroll
      for (int v = 0; v < 2; ++v) {
        int j = (wave >> 1) * 64 + v * 32 + l31;
        bw[v] = *(const bf16x8*)&Pt[j * 64 + ((c ^ ((j ^ (j >> 3)) & 7)) << 3)];
      }
#pragma unroll
      for (int u = 0; u < 2; ++u)
#pragma unroll
        for (int v = 0; v < 2; ++v)
          acc[u][v] = __builtin_amdgcn_mfma_f32_32x32x16_bf16(af[u], bw[v], acc[u][v], 0, 0, 0);
    }
    // prefetch next-iter A fragments (overlaps MFMA)
    if (it < 31) {
      int t_row = tbase + (it + 1) * 64 + s_tt * 32 + l31;
#pragma unroll
      for (int kk = 0; kk < 4; ++kk)
        aR[kk] = *(const bf16x8*)(DHbT + (size_t)t_row * 64 + kk * 16 + h * 8);
    }
    __syncthreads();  // all waves done reading Hs/Pt before overwrite
  }
  // ---- epilogue: atomic accumulate into Z (t-split 4 collisions) ----
#pragma unroll
  for (int u = 0; u < 2; ++u)
#pragma unroll
    for (int v = 0; v < 2; ++v)
#pragma unroll
      for (int r = 0; r < 16; ++r) {
        int d = dh * 128 + (wave & 1) * 64 + u * 32 + (r & 3) + 8 * (r >> 2) + 4 * h;
        int j = j0 + (wave >> 1) * 64 + v * 32 + l31;
        atomicAdd(&Z[(size_t)d * T_DIM + j], acc[u][v][r] * l2v);
      }
}

// ---------------------------------------------------------------------------
extern "C" void kernel_launch(void* const* d_in, const int* in_sizes, int n_in,
                              void* d_out, int out_size, void* d_ws,
                              size_t ws_size, hipStream_t stream) {
  (void)in_sizes; (void)n_in; (void)out_size; (void)ws_size;
  const float* H = (const float*)d_in[0];
  const float* Dm = (const float*)d_in[1];
  const float* l2 = (const float*)d_in[2];
  float* Z = (float*)d_out;
  char* ws = (char*)d_ws;
  __bf16* DHbT = (__bf16*)ws;                       // 1,048,576 B
  float* lb = (float*)(ws + 1048576);               // 32,768 B
  float* rowsum = (float*)(ws + 1048576 + 32768);   // 32,768 B
  __bf16* Hbf_sw = (__bf16*)(ws + 1048576 + 65536); // 4,194,304 B

  k_dh<<<128, 256, 0, stream>>>(H, Dm, DHbT, lb, rowsum);
  k_rowsum<<<1024, 256, 0, stream>>>(DHbT, lb, rowsum);
  k_scaleH<<<256, 256, 0, stream>>>(H, rowsum, Hbf_sw, Z);
  k_z<<<512, 256, 0, stream>>>(Hbf_sw, DHbT, lb, l2, Z);
}